// Round 1
// baseline (323.387 us; speedup 1.0000x reference)
//
#include <hip/hip_runtime.h>

// GroupDRO loss: per-sample 3-class CE, group = mean(logits)<0.4 ? 0 : 1,
// subgroup = group*3 + label. Only 6 subgroup sums are needed; group sums,
// total CE, and combined loss derive from them in a tiny finalize kernel.

constexpr int N_SAMPLES = 16777216;
constexpr int BLOCK = 256;
constexpr int GRID = 2048;          // 8192 waves -> full device, 8 quad-iters/thread
constexpr int WAVES = BLOCK / 64;

__global__ __launch_bounds__(BLOCK) void dro_partial(
    const float* __restrict__ logits,
    const int*   __restrict__ labels,
    float*       __restrict__ bins)   // 6 floats in d_ws, pre-zeroed
{
    const int nq = N_SAMPLES / 4;     // process 4 samples (12 floats) per iter
    const float4* __restrict__ lg = (const float4*)logits;
    const int4*   __restrict__ lb = (const int4*)labels;

    float acc[6] = {0.f, 0.f, 0.f, 0.f, 0.f, 0.f};

    for (int q = blockIdx.x * BLOCK + threadIdx.x; q < nq; q += GRID * BLOCK) {
        float4 p0 = lg[3 * q + 0];
        float4 p1 = lg[3 * q + 1];
        float4 p2 = lg[3 * q + 2];
        int4   l4 = lb[q];

        float xs[12] = {p0.x, p0.y, p0.z, p0.w, p1.x, p1.y,
                        p1.z, p1.w, p2.x, p2.y, p2.z, p2.w};
        int   ls[4]  = {l4.x, l4.y, l4.z, l4.w};

        #pragma unroll
        for (int s = 0; s < 4; ++s) {
            float a = xs[3 * s], b = xs[3 * s + 1], c = xs[3 * s + 2];
            int lab = ls[s];

            float m  = fmaxf(a, fmaxf(b, c));
            float ea = __expf(a - m), eb = __expf(b - m), ec = __expf(c - m);
            float lse = m + __logf(ea + eb + ec);
            float xl = (lab == 0) ? a : ((lab == 1) ? b : c);
            float ce = lse - xl;

            float mean = (a + b + c) * (1.0f / 3.0f);
            int g  = (mean < 0.4f) ? 0 : 1;
            int sg = g * 3 + lab;

            #pragma unroll
            for (int j = 0; j < 6; ++j)
                acc[j] += (j == sg) ? ce : 0.0f;   // branchless scatter
        }
    }

    // wave reduce (64 lanes)
    #pragma unroll
    for (int j = 0; j < 6; ++j) {
        #pragma unroll
        for (int off = 32; off > 0; off >>= 1)
            acc[j] += __shfl_down(acc[j], off, 64);
    }

    __shared__ float lds[WAVES][6];
    int wave = threadIdx.x >> 6;
    int lane = threadIdx.x & 63;
    if (lane == 0) {
        #pragma unroll
        for (int j = 0; j < 6; ++j) lds[wave][j] = acc[j];
    }
    __syncthreads();

    if (threadIdx.x < 6) {
        float s = 0.f;
        #pragma unroll
        for (int w = 0; w < WAVES; ++w) s += lds[w][threadIdx.x];
        atomicAdd(&bins[threadIdx.x], s);   // device-scope by default
    }
}

__global__ void dro_finalize(const float* __restrict__ bins,
                             const float* __restrict__ gw,
                             float* __restrict__ out)
{
    if (threadIdx.x == 0 && blockIdx.x == 0) {
        float sg[6];
        float tot = 0.f;
        #pragma unroll
        for (int j = 0; j < 6; ++j) { sg[j] = bins[j]; tot += sg[j]; }
        float g0 = sg[0] + sg[1] + sg[2];
        float g1 = sg[3] + sg[4] + sg[5];
        float total_loss = g0 * gw[0] + g1 * gw[1];
        float standard   = tot / (float)N_SAMPLES;
        float combined   = 0.7f * standard + 0.3f * total_loss;
        out[0] = combined;
        out[1] = g0;
        out[2] = g1;
        #pragma unroll
        for (int j = 0; j < 6; ++j) out[3 + j] = sg[j];
    }
}

extern "C" void kernel_launch(void* const* d_in, const int* in_sizes, int n_in,
                              void* d_out, int out_size, void* d_ws, size_t ws_size,
                              hipStream_t stream) {
    const float* logits = (const float*)d_in[0];
    const int*   labels = (const int*)d_in[1];
    const float* gw     = (const float*)d_in[2];
    float* bins = (float*)d_ws;       // 6 fp32 accumulators
    float* out  = (float*)d_out;      // [combined, group0, group1, sub0..sub5]

    hipMemsetAsync(bins, 0, 6 * sizeof(float), stream);
    dro_partial<<<GRID, BLOCK, 0, stream>>>(logits, labels, bins);
    dro_finalize<<<1, 64, 0, stream>>>(bins, gw, out);
}

// Round 2
// 319.759 us; speedup vs baseline: 1.0113x; 1.0113x over previous
//
#include <hip/hip_runtime.h>

// GroupDRO loss: per-sample 3-class CE, group = mean(logits)<0.4 ? 0 : 1,
// subgroup = group*3 + label. Only 6 subgroup sums are needed; group sums,
// total CE, and combined loss derive from them in the finalize kernel.
//
// R1 -> R2: compile-time trip count (16 quads/thread, unroll 2 for 128 B/lane
// MLP), per-block partials in d_ws instead of memset+atomics (2 dispatches).

constexpr int N_SAMPLES = 16777216;
constexpr int NQ = N_SAMPLES / 4;          // 4,194,304 quad-samples
constexpr int BLOCK = 256;
constexpr int GRID = 1024;                 // 262,144 threads
constexpr int STRIDE = GRID * BLOCK;
constexpr int ITERS = NQ / STRIDE;         // exactly 16, no tail
constexpr int WAVES = BLOCK / 64;

static_assert(ITERS * STRIDE == NQ, "exact tiling");

__global__ __launch_bounds__(BLOCK) void dro_partial(
    const float* __restrict__ logits,
    const int*   __restrict__ labels,
    float*       __restrict__ partials)    // [GRID][6] in d_ws (overwritten)
{
    const float4* __restrict__ lg = (const float4*)logits;
    const int4*   __restrict__ lb = (const int4*)labels;

    float acc[6] = {0.f, 0.f, 0.f, 0.f, 0.f, 0.f};
    const int base = blockIdx.x * BLOCK + threadIdx.x;

    #pragma unroll 2
    for (int it = 0; it < ITERS; ++it) {
        const int q = base + it * STRIDE;
        float4 p0 = lg[3 * q + 0];
        float4 p1 = lg[3 * q + 1];
        float4 p2 = lg[3 * q + 2];
        int4   l4 = lb[q];

        float xs[12] = {p0.x, p0.y, p0.z, p0.w, p1.x, p1.y,
                        p1.z, p1.w, p2.x, p2.y, p2.z, p2.w};
        int   ls[4]  = {l4.x, l4.y, l4.z, l4.w};

        #pragma unroll
        for (int s = 0; s < 4; ++s) {
            float a = xs[3 * s], b = xs[3 * s + 1], c = xs[3 * s + 2];
            int lab = ls[s];

            float m  = fmaxf(a, fmaxf(b, c));
            float ea = __expf(a - m), eb = __expf(b - m), ec = __expf(c - m);
            float lse = m + __logf(ea + eb + ec);
            float xl = (lab == 0) ? a : ((lab == 1) ? b : c);
            float ce = lse - xl;

            float mean = (a + b + c) * (1.0f / 3.0f);
            int g  = (mean < 0.4f) ? 0 : 1;
            int sg = g * 3 + lab;

            #pragma unroll
            for (int j = 0; j < 6; ++j)
                acc[j] += (j == sg) ? ce : 0.0f;   // branchless scatter
        }
    }

    // wave reduce (64 lanes)
    #pragma unroll
    for (int j = 0; j < 6; ++j) {
        #pragma unroll
        for (int off = 32; off > 0; off >>= 1)
            acc[j] += __shfl_down(acc[j], off, 64);
    }

    __shared__ float lds[WAVES][6];
    const int wave = threadIdx.x >> 6;
    const int lane = threadIdx.x & 63;
    if (lane == 0) {
        #pragma unroll
        for (int j = 0; j < 6; ++j) lds[wave][j] = acc[j];
    }
    __syncthreads();

    if (threadIdx.x < 6) {
        float s = 0.f;
        #pragma unroll
        for (int w = 0; w < WAVES; ++w) s += lds[w][threadIdx.x];
        partials[blockIdx.x * 6 + threadIdx.x] = s;  // no atomics, no pre-zero
    }
}

__global__ __launch_bounds__(BLOCK) void dro_finalize(
    const float* __restrict__ partials,    // [GRID][6]
    const float* __restrict__ gw,
    float* __restrict__ out)
{
    float acc[6] = {0.f, 0.f, 0.f, 0.f, 0.f, 0.f};
    for (int b = threadIdx.x; b < GRID; b += BLOCK) {
        #pragma unroll
        for (int j = 0; j < 6; ++j) acc[j] += partials[b * 6 + j];
    }

    #pragma unroll
    for (int j = 0; j < 6; ++j) {
        #pragma unroll
        for (int off = 32; off > 0; off >>= 1)
            acc[j] += __shfl_down(acc[j], off, 64);
    }

    __shared__ float lds[WAVES][6];
    const int wave = threadIdx.x >> 6;
    const int lane = threadIdx.x & 63;
    if (lane == 0) {
        #pragma unroll
        for (int j = 0; j < 6; ++j) lds[wave][j] = acc[j];
    }
    __syncthreads();

    if (threadIdx.x == 0) {
        float sg[6];
        float tot = 0.f;
        #pragma unroll
        for (int j = 0; j < 6; ++j) {
            float s = 0.f;
            #pragma unroll
            for (int w = 0; w < WAVES; ++w) s += lds[w][j];
            sg[j] = s;
            tot += s;
        }
        float g0 = sg[0] + sg[1] + sg[2];
        float g1 = sg[3] + sg[4] + sg[5];
        float total_loss = g0 * gw[0] + g1 * gw[1];
        float standard   = tot / (float)N_SAMPLES;
        float combined   = 0.7f * standard + 0.3f * total_loss;
        out[0] = combined;
        out[1] = g0;
        out[2] = g1;
        #pragma unroll
        for (int j = 0; j < 6; ++j) out[3 + j] = sg[j];
    }
}

extern "C" void kernel_launch(void* const* d_in, const int* in_sizes, int n_in,
                              void* d_out, int out_size, void* d_ws, size_t ws_size,
                              hipStream_t stream) {
    const float* logits = (const float*)d_in[0];
    const int*   labels = (const int*)d_in[1];
    const float* gw     = (const float*)d_in[2];
    float* partials = (float*)d_ws;    // GRID*6 floats, fully overwritten
    float* out      = (float*)d_out;   // [combined, g0, g1, sg0..sg5]

    dro_partial<<<GRID, BLOCK, 0, stream>>>(logits, labels, partials);
    dro_finalize<<<1, BLOCK, 0, stream>>>(partials, gw, out);
}